// Round 1
// baseline (110303.979 us; speedup 1.0000x reference)
//
#include <hip/hip_runtime.h>
#include <cstdint>

#define B_   8
#define S_   512
#define D_   768
#define C_   9
#define BS_  4096   // B*S

// ---------------------------------------------------------------------------
// embedding gather: x[row][0:768] = emb[ids[row]][0:768]
// ---------------------------------------------------------------------------
__global__ __launch_bounds__(192) void k_embed(const int* __restrict__ ids,
                                               const float* __restrict__ emb,
                                               float* __restrict__ x) {
  int row = blockIdx.x;
  int id = ids[row];
  const float4* src = (const float4*)(emb + (size_t)id * D_);
  float4* dst = (float4*)(x + (size_t)row * D_);
  dst[threadIdx.x] = src[threadIdx.x];
}

// ---------------------------------------------------------------------------
// generic fp32 GEMM: C[M,N] = A[M,K] @ W[N,K]^T + bias[N], act: 0 none 1 relu 2 sigmoid
// 128x128 tile, BK=16, 256 threads, 8x8 micro-tile.
// LDS layout swizzle: GIDX(k,m) spreads 32-float blocks across banks.
// ---------------------------------------------------------------------------
#define GIDX(k, m) ((k)*144 + (m) + (((m) >> 5) << 2))

__global__ __launch_bounds__(256) void k_gemm(const float* __restrict__ A,
                                              const float* __restrict__ W,
                                              const float* __restrict__ bias,
                                              float* __restrict__ C,
                                              int M, int N, int K, int act) {
  __shared__ float As[2304];
  __shared__ float Bs[2304];
  int bm0 = blockIdx.y * 128, bn0 = blockIdx.x * 128;
  int tid = threadIdx.x;
  int tm = tid >> 4, tn = tid & 15;
  float acc[8][8];
#pragma unroll
  for (int i = 0; i < 8; ++i)
#pragma unroll
    for (int j = 0; j < 8; ++j) acc[i][j] = 0.f;

  for (int k0 = 0; k0 < K; k0 += 16) {
    __syncthreads();
#pragma unroll
    for (int j = 0; j < 2; ++j) {
      int f4 = tid + j * 256;          // 0..511
      int r = f4 >> 2;
      int kq = (f4 & 3) * 4;
      float4 va = *(const float4*)(A + (size_t)(bm0 + r) * K + k0 + kq);
      As[GIDX(kq + 0, r)] = va.x; As[GIDX(kq + 1, r)] = va.y;
      As[GIDX(kq + 2, r)] = va.z; As[GIDX(kq + 3, r)] = va.w;
      float4 vb = *(const float4*)(W + (size_t)(bn0 + r) * K + k0 + kq);
      Bs[GIDX(kq + 0, r)] = vb.x; Bs[GIDX(kq + 1, r)] = vb.y;
      Bs[GIDX(kq + 2, r)] = vb.z; Bs[GIDX(kq + 3, r)] = vb.w;
    }
    __syncthreads();
#pragma unroll
    for (int kk = 0; kk < 16; ++kk) {
      float a[8], b[8];
      *(float4*)&a[0] = *(const float4*)&As[GIDX(kk, tm * 8)];
      *(float4*)&a[4] = *(const float4*)&As[GIDX(kk, tm * 8 + 4)];
      *(float4*)&b[0] = *(const float4*)&Bs[GIDX(kk, tn * 8)];
      *(float4*)&b[4] = *(const float4*)&Bs[GIDX(kk, tn * 8 + 4)];
#pragma unroll
      for (int i = 0; i < 8; ++i)
#pragma unroll
        for (int j = 0; j < 8; ++j) acc[i][j] += a[i] * b[j];
    }
  }

  float bv[8];
#pragma unroll
  for (int j = 0; j < 8; ++j) bv[j] = bias[bn0 + tn * 8 + j];
#pragma unroll
  for (int i = 0; i < 8; ++i) {
    int row = bm0 + tm * 8 + i;
    float o[8];
#pragma unroll
    for (int j = 0; j < 8; ++j) {
      float v = acc[i][j] + bv[j];
      if (act == 1) v = fmaxf(v, 0.f);
      else if (act == 2) v = 1.f / (1.f + expf(-v));
      o[j] = v;
    }
    float* cp = C + (size_t)row * N + bn0 + tn * 8;
    *(float4*)cp = make_float4(o[0], o[1], o[2], o[3]);
    *(float4*)(cp + 4) = make_float4(o[4], o[5], o[6], o[7]);
  }
}

// ---------------------------------------------------------------------------
// highway combine (in place): x = t*hh + (1-t)*x
// ---------------------------------------------------------------------------
__global__ __launch_bounds__(256) void k_highway(float* __restrict__ x,
                                                 const float* __restrict__ hh,
                                                 const float* __restrict__ tt) {
  const int n4 = BS_ * D_ / 4;
  for (int i = blockIdx.x * 256 + threadIdx.x; i < n4; i += gridDim.x * 256) {
    float4 xv = ((const float4*)x)[i];
    float4 hv = ((const float4*)hh)[i];
    float4 tv = ((const float4*)tt)[i];
    xv.x = tv.x * hv.x + (1.f - tv.x) * xv.x;
    xv.y = tv.y * hv.y + (1.f - tv.y) * xv.y;
    xv.z = tv.z * hv.z + (1.f - tv.z) * xv.z;
    xv.w = tv.w * hv.w + (1.f - tv.w) * xv.w;
    ((float4*)x)[i] = xv;
  }
}

// ---------------------------------------------------------------------------
// multi-head attention. qkv: [4096][2304] (q|k|v). out: [4096][768].
// block = one (b,h) pair x 16-row q-tile; 256 threads.
// ---------------------------------------------------------------------------
__global__ __launch_bounds__(256) void k_attn(const float* __restrict__ qkv,
                                              float* __restrict__ out) {
  __shared__ float Qs[16 * 100];
  __shared__ float Ks[32 * 101];
  __shared__ float Ps[16 * 513];
  int bh = blockIdx.x;          // 0..63
  int b = bh >> 3, h = bh & 7;
  int q0 = blockIdx.y * 16;
  int tid = threadIdx.x;
  const float scale = 0.10206207261596577f;  // 1/sqrt(96)

  const float* qb = qkv + (size_t)(b * 512 + q0) * 2304 + h * 96;
  for (int i = tid; i < 16 * 96; i += 256) {
    int r = i / 96, c = i - r * 96;
    Qs[r * 100 + c] = qb[(size_t)r * 2304 + c];
  }
  int qi = tid >> 4, kseg = tid & 15;

  for (int kt = 0; kt < 16; ++kt) {
    __syncthreads();
    const float* kb = qkv + (size_t)(b * 512 + kt * 32) * 2304 + 768 + h * 96;
    for (int i = tid; i < 32 * 96; i += 256) {
      int r = i / 96, c = i - r * 96;
      Ks[r * 101 + c] = kb[(size_t)r * 2304 + c];
    }
    __syncthreads();
    int kj0 = kseg * 2;
    float s0 = 0.f, s1 = 0.f;
    const float* qrow = &Qs[qi * 100];
    const float* k0p = &Ks[kj0 * 101];
    const float* k1p = &Ks[(kj0 + 1) * 101];
#pragma unroll 8
    for (int d = 0; d < 96; ++d) {
      float qv = qrow[d];
      s0 += qv * k0p[d];
      s1 += qv * k1p[d];
    }
    Ps[qi * 513 + kt * 32 + kj0] = s0 * scale;
    Ps[qi * 513 + kt * 32 + kj0 + 1] = s1 * scale;
  }
  __syncthreads();

  // softmax over each row (16 lanes per row, strided elements)
  {
    float m = -1e30f;
    for (int j = 0; j < 32; ++j) m = fmaxf(m, Ps[qi * 513 + kseg + j * 16]);
    m = fmaxf(m, __shfl_xor(m, 1)); m = fmaxf(m, __shfl_xor(m, 2));
    m = fmaxf(m, __shfl_xor(m, 4)); m = fmaxf(m, __shfl_xor(m, 8));
    float sum = 0.f;
    for (int j = 0; j < 32; ++j) {
      int idx = qi * 513 + kseg + j * 16;
      float e = expf(Ps[idx] - m);
      Ps[idx] = e;
      sum += e;
    }
    sum += __shfl_xor(sum, 1); sum += __shfl_xor(sum, 2);
    sum += __shfl_xor(sum, 4); sum += __shfl_xor(sum, 8);
    float inv = 1.f / sum;
    for (int j = 0; j < 32; ++j) Ps[qi * 513 + kseg + j * 16] *= inv;
  }

  // O = P @ V
  float acc[6] = {0.f, 0.f, 0.f, 0.f, 0.f, 0.f};
  int d0 = kseg * 6;
  for (int kt = 0; kt < 16; ++kt) {
    __syncthreads();
    const float* vb = qkv + (size_t)(b * 512 + kt * 32) * 2304 + 1536 + h * 96;
    for (int i = tid; i < 32 * 96; i += 256) {
      int r = i / 96, c = i - r * 96;
      Ks[r * 101 + c] = vb[(size_t)r * 2304 + c];
    }
    __syncthreads();
#pragma unroll 4
    for (int kj = 0; kj < 32; ++kj) {
      float p = Ps[qi * 513 + kt * 32 + kj];
      const float* vrow = &Ks[kj * 101 + d0];
#pragma unroll
      for (int u = 0; u < 6; ++u) acc[u] += p * vrow[u];
    }
  }
  float* ob = out + (size_t)(b * 512 + q0 + qi) * 768 + h * 96 + d0;
#pragma unroll
  for (int u = 0; u < 6; ++u) ob[u] = acc[u];
}

// ---------------------------------------------------------------------------
// persistent BiLSTM recurrence, one layer (both directions), 192 WGs x 256.
// gates: [B*S][6144] = x@Wih^T+b (dir0 cols 0..3071, dir1 cols 3072..6143)
// Whh:   [2][3072][768]; hbuf: [2 dir][2 parity][768*8]; hs: [B*S][1536]
// bar:   per-dir monotonic barrier counters (bar[0], bar[32]) - pre-zeroed.
// ---------------------------------------------------------------------------
#define NWGD 96
__global__ __launch_bounds__(256) void k_lstm(const float* __restrict__ gates,
                                              const float* __restrict__ Whh,
                                              float* __restrict__ hbuf,
                                              float* __restrict__ hs,
                                              int* __restrict__ bar) {
  __shared__ float hlds[6176];
  int tid = threadIdx.x;
  int lane = tid & 63;
  int widx = tid >> 6;
  int wg = blockIdx.x;
  int dir = wg / NWGD;
  int ww = (wg % NWGD) * 4 + widx;          // 0..383
  int r = lane & 7;
  int s = lane >> 3;
  int jj = (lane >> 2) & 1;
  int gate = lane & 3;
  int hidden = ww * 2 + jj;
  int wrow = gate * 768 + hidden;           // row of Whh / gate column index
  int bb = (((lane >> 3) & 1) << 2) | (((lane >> 4) & 1) << 1) | ((lane >> 5) & 1);
  bool owner = (gate == 0);

  // hold my 96-wide K-slice of Whh[dir][wrow] in registers
  float w[96];
  {
    const float* wp = Whh + ((size_t)dir * 3072 + wrow) * 768 + s * 96;
#pragma unroll
    for (int i = 0; i < 24; ++i) {
      float4 v = *(const float4*)(wp + i * 4);
      w[i * 4 + 0] = v.x; w[i * 4 + 1] = v.y; w[i * 4 + 2] = v.z; w[i * 4 + 3] = v.w;
    }
  }

  float* hb = hbuf + (size_t)dir * 2 * 6144;
  int* barp = bar + dir * 32;
  float cst = 0.f;

  int t0 = dir ? 511 : 0;
  float gq = gates[((size_t)(bb * 512 + t0)) * 6144 + dir * 3072 + wrow];

  for (int step = 0; step < 512; ++step) {
    int t = dir ? (511 - step) : step;
    // stage h(t) into LDS with per-96-row skew (bank-conflict-free b128 reads)
    {
      const float4* src = (const float4*)(hb + (step & 1) * 6144);
#pragma unroll
      for (int i = 0; i < 6; ++i) {
        int fi = i * 256 + tid;
        float4 v = src[fi];
        int f0 = fi * 4;
        *(float4*)&hlds[f0 + ((f0 / 768) << 2)] = v;
      }
    }
    __syncthreads();

    float acc[8];
#pragma unroll
    for (int i = 0; i < 8; ++i) acc[i] = 0.f;
    {
      const float* hp = hlds + s * 772;
#pragma unroll
      for (int i = 0; i < 96; ++i) {
        float wv = w[i];
        float4 h0 = *(const float4*)(hp + i * 8);
        float4 h1 = *(const float4*)(hp + i * 8 + 4);
        acc[0] = fmaf(wv, h0.x, acc[0]); acc[1] = fmaf(wv, h0.y, acc[1]);
        acc[2] = fmaf(wv, h0.z, acc[2]); acc[3] = fmaf(wv, h0.w, acc[3]);
        acc[4] = fmaf(wv, h1.x, acc[4]); acc[5] = fmaf(wv, h1.y, acc[5]);
        acc[6] = fmaf(wv, h1.z, acc[6]); acc[7] = fmaf(wv, h1.w, acc[7]);
      }
    }

    // prefetch next step's precomputed gate value
    float gq_next = 0.f;
    if (step < 511) {
      int tn = dir ? (511 - step - 1) : (step + 1);
      gq_next = gates[((size_t)(bb * 512 + tn)) * 6144 + dir * 3072 + wrow];
    }

    // reduce-scatter across the 8 K-slices (lane bits 3,4,5); end: acc[0] = dot for batch bb
    {
      bool hi = (lane & 8) != 0;
      float s0 = hi ? acc[0] : acc[4], s1 = hi ? acc[1] : acc[5];
      float s2 = hi ? acc[2] : acc[6], s3 = hi ? acc[3] : acc[7];
      float k0 = hi ? acc[4] : acc[0], k1 = hi ? acc[5] : acc[1];
      float k2 = hi ? acc[6] : acc[2], k3 = hi ? acc[7] : acc[3];
      acc[0] = k0 + __shfl_xor(s0, 8); acc[1] = k1 + __shfl_xor(s1, 8);
      acc[2] = k2 + __shfl_xor(s2, 8); acc[3] = k3 + __shfl_xor(s3, 8);
    }
    {
      bool hi = (lane & 16) != 0;
      float s0 = hi ? acc[0] : acc[2], s1 = hi ? acc[1] : acc[3];
      float k0 = hi ? acc[2] : acc[0], k1 = hi ? acc[3] : acc[1];
      acc[0] = k0 + __shfl_xor(s0, 16); acc[1] = k1 + __shfl_xor(s1, 16);
    }
    {
      bool hi = (lane & 32) != 0;
      float s0 = hi ? acc[0] : acc[1];
      float k0 = hi ? acc[1] : acc[0];
      acc[0] = k0 + __shfl_xor(s0, 32);
    }

    float g = acc[0] + gq;
    gq = gq_next;
    float g1 = __shfl_down(g, 1);
    float g2 = __shfl_down(g, 2);
    float g3 = __shfl_down(g, 3);
    if (owner) {
      float i_ = 1.f / (1.f + expf(-g));
      float f_ = 1.f / (1.f + expf(-g1));
      float ci = tanhf(g2);
      float o_ = 1.f / (1.f + expf(-g3));
      cst = f_ * cst + i_ * ci;
      float hnew = o_ * tanhf(cst);
      hb[((step + 1) & 1) * 6144 + hidden * 8 + bb] = hnew;
      hs[((size_t)(bb * 512 + t)) * 1536 + dir * 768 + hidden] = hnew;
    }

    // per-direction grid barrier (monotonic counter)
    __threadfence();
    __syncthreads();
    if (tid == 0) {
      __hip_atomic_fetch_add(barp, 1, __ATOMIC_RELEASE, __HIP_MEMORY_SCOPE_AGENT);
      int target = (step + 1) * NWGD;
      while (__hip_atomic_load(barp, __ATOMIC_ACQUIRE, __HIP_MEMORY_SCOPE_AGENT) < target)
        __builtin_amdgcn_s_sleep(8);
    }
    __syncthreads();
    __threadfence();
  }
}

// ---------------------------------------------------------------------------
// fc: em[4096][9] = A[4096][1536] @ fcW[9][1536]^T + fcb. Wave per row.
// ---------------------------------------------------------------------------
__global__ __launch_bounds__(256) void k_fc(const float* __restrict__ A,
                                            const float* __restrict__ Wf,
                                            const float* __restrict__ bf,
                                            float* __restrict__ out) {
  __shared__ float Wl[9 * 1536];
  int tid = threadIdx.x;
  for (int i = tid; i < 9 * 1536; i += 256) Wl[i] = Wf[i];
  __syncthreads();
  int lane = tid & 63, wv = tid >> 6;
  int row = blockIdx.x * 4 + wv;
  const float* a = A + (size_t)row * 1536;
  float acc[9];
#pragma unroll
  for (int c = 0; c < 9; ++c) acc[c] = 0.f;
  for (int i = 0; i < 24; ++i) {
    float av = a[lane + i * 64];
#pragma unroll
    for (int c = 0; c < 9; ++c) acc[c] += av * Wl[c * 1536 + lane + i * 64];
  }
#pragma unroll
  for (int c = 0; c < 9; ++c) {
#pragma unroll
    for (int m = 1; m < 64; m <<= 1) acc[c] += __shfl_xor(acc[c], m);
  }
  if (lane == 0) {
#pragma unroll
    for (int c = 0; c < 9; ++c) out[(size_t)row * 9 + c] = acc[c] + bf[c];
  }
}

// ---------------------------------------------------------------------------
// CRF: forward logsumexp + numerator + Viterbi + backtrace. Single block.
// out[0] = loss; out[1 + b*512 + t] = decoded tag (as float).
// ---------------------------------------------------------------------------
__global__ __launch_bounds__(128) void k_crf(const float* __restrict__ em,
                                             const int* __restrict__ labels,
                                             const float* __restrict__ cs,
                                             const float* __restrict__ ce,
                                             const float* __restrict__ ct,
                                             float* __restrict__ out) {
  __shared__ float trans[9][12];
  __shared__ float ab[2][8][9];
  __shared__ float vb[2][8][9];
  __shared__ unsigned char bps[511][8][9];
  __shared__ float red[128];
  __shared__ float lz[8];
  int tid = threadIdx.x;
  if (tid < 81) trans[tid / 9][tid % 9] = ct[tid];
  if (tid < 72) {
    int b = tid / 9, c = tid % 9;
    float v = cs[c] + em[(b * 512) * 9 + c];
    ab[0][b][c] = v;
    vb[0][b][c] = v;
  }
  __syncthreads();
  for (int t = 1; t < 512; ++t) {
    int rp = (t - 1) & 1, wp = t & 1;
    if (tid < 72) {
      int b = tid / 9, cn = tid % 9;
      float e = em[(b * 512 + t) * 9 + cn];
      float m = -1e30f, vm = -1e30f;
      int bp = 0;
#pragma unroll
      for (int cp = 0; cp < 9; ++cp) {
        float x = ab[rp][b][cp] + trans[cp][cn];
        m = fmaxf(m, x);
        float y = vb[rp][b][cp] + trans[cp][cn];
        if (y > vm) { vm = y; bp = cp; }
      }
      float ssum = 0.f;
#pragma unroll
      for (int cp = 0; cp < 9; ++cp)
        ssum += expf(ab[rp][b][cp] + trans[cp][cn] - m);
      ab[wp][b][cn] = m + logf(ssum) + e;
      vb[wp][b][cn] = vm + e;
      bps[t - 1][b][cn] = (unsigned char)bp;
    }
    __syncthreads();
  }
  // numerator
  float part = 0.f;
  for (int idx = tid; idx < 4096; idx += 128) {
    int b = idx >> 9, t = idx & 511;
    int tg = labels[b * 512 + t];
    part += em[(b * 512 + t) * 9 + tg];
    if (t < 511) part += trans[tg][labels[b * 512 + t + 1]];
  }
  if (tid < 8) part += cs[labels[tid * 512]] + ce[labels[tid * 512 + 511]];
  red[tid] = part;
  __syncthreads();
  for (int s2 = 64; s2 > 0; s2 >>= 1) {
    if (tid < s2) red[tid] += red[tid + s2];
    __syncthreads();
  }
  if (tid < 8) {
    int b = tid;
    float m = -1e30f;
#pragma unroll
    for (int c = 0; c < 9; ++c) m = fmaxf(m, ab[1][b][c] + ce[c]);
    float ssum = 0.f;
#pragma unroll
    for (int c = 0; c < 9; ++c) ssum += expf(ab[1][b][c] + ce[c] - m);
    lz[b] = m + logf(ssum);
  }
  __syncthreads();
  if (tid == 0) {
    float z = 0.f;
#pragma unroll
    for (int b = 0; b < 8; ++b) z += lz[b];
    out[0] = -(red[0] - z);
  }
  if (tid < 8) {
    int b = tid;
    float bv2 = vb[1][b][0] + ce[0];
    int best = 0;
#pragma unroll
    for (int c = 1; c < 9; ++c) {
      float y = vb[1][b][c] + ce[c];
      if (y > bv2) { bv2 = y; best = c; }
    }
    out[1 + b * 512 + 511] = (float)best;
    int tg = best;
    for (int t = 510; t >= 0; --t) {
      tg = bps[t][b][tg];
      out[1 + b * 512 + t] = (float)tg;
    }
  }
}

// ---------------------------------------------------------------------------
extern "C" void kernel_launch(void* const* d_in, const int* in_sizes, int n_in,
                              void* d_out, int out_size, void* d_ws, size_t ws_size,
                              hipStream_t stream) {
  (void)in_sizes; (void)n_in; (void)out_size; (void)ws_size;
  const int*   ids    = (const int*)d_in[0];
  const int*   labels = (const int*)d_in[1];
  const float* emb    = (const float*)d_in[2];
  const float* hwWh   = (const float*)d_in[3];
  const float* hwbh   = (const float*)d_in[4];
  const float* hwWt   = (const float*)d_in[5];
  const float* hwbt   = (const float*)d_in[6];
  const float* ipw    = (const float*)d_in[7];
  const float* ipb    = (const float*)d_in[8];
  const float* opw    = (const float*)d_in[9];
  const float* opb    = (const float*)d_in[10];
  const float* l0Wih  = (const float*)d_in[11];
  const float* l0Whh  = (const float*)d_in[12];
  const float* l0b    = (const float*)d_in[13];
  const float* l1Wih  = (const float*)d_in[14];
  const float* l1Whh  = (const float*)d_in[15];
  const float* l1b    = (const float*)d_in[16];
  const float* fcW    = (const float*)d_in[17];
  const float* fcb    = (const float*)d_in[18];
  const float* cs     = (const float*)d_in[19];
  const float* ce     = (const float*)d_in[20];
  const float* ct     = (const float*)d_in[21];

  float* ws   = (float*)d_ws;
  float* x0   = ws;                 // 3,145,728  (embed/highway out; later attn out)
  float* gbuf = ws + 3145728;       // 25,165,824 (hh|tt, later qkv, later gates)
  float* hh   = gbuf;
  float* tt   = gbuf + 3145728;
  float* qkv  = gbuf + 6291456;     // 9,437,184
  float* x1   = ws + 28311552;      // 3,145,728  (attn out_proj)
  float* hs0  = ws + 31457280;      // 6,291,456
  float* hs1  = ws + 37748736;      // 6,291,456
  float* em   = ws + 44040192;      // 36,864
  float* hbuf = ws + 44077056;      // 24,576
  int*   bar  = (int*)(ws + 44101632);  // 64 ints

  dim3 g768(6, 32), g2304(18, 32), g6144(48, 32);

  k_embed<<<BS_, 192, 0, stream>>>(ids, emb, x0);
  k_gemm<<<g768, 256, 0, stream>>>(x0, hwWh, hwbh, hh, BS_, 768, 768, 1);
  k_gemm<<<g768, 256, 0, stream>>>(x0, hwWt, hwbt, tt, BS_, 768, 768, 2);
  k_highway<<<768, 256, 0, stream>>>(x0, hh, tt);
  k_gemm<<<g2304, 256, 0, stream>>>(x0, ipw, ipb, qkv, BS_, 2304, 768, 0);
  k_attn<<<dim3(64, 32), 256, 0, stream>>>(qkv, x0);           // x0 = attn output
  k_gemm<<<g768, 256, 0, stream>>>(x0, opw, opb, x1, BS_, 768, 768, 0);

  // layer 0 gates precompute (both dirs fused: W [6144][768], bias [6144])
  k_gemm<<<g6144, 256, 0, stream>>>(x1, l0Wih, l0b, gbuf, BS_, 6144, 768, 0);
  hipMemsetAsync(hbuf, 0, (24576 + 64) * sizeof(float), stream);
  k_lstm<<<192, 256, 0, stream>>>(gbuf, l0Whh, hbuf, hs0, bar);

  // layer 1
  k_gemm<<<g6144, 256, 0, stream>>>(hs0, l1Wih, l1b, gbuf, BS_, 6144, 1536, 0);
  hipMemsetAsync(hbuf, 0, (24576 + 64) * sizeof(float), stream);
  k_lstm<<<192, 256, 0, stream>>>(gbuf, l1Whh, hbuf, hs1, bar);

  k_fc<<<1024, 256, 0, stream>>>(hs1, fcW, fcb, em);
  k_crf<<<1, 128, 0, stream>>>(em, labels, cs, ce, ct, (float*)d_out);
}

// Round 2
// 9781.790 us; speedup vs baseline: 11.2765x; 11.2765x over previous
//
#include <hip/hip_runtime.h>
#include <cstdint>

#define B_   8
#define S_   512
#define D_   768
#define C_   9
#define BS_  4096   // B*S

// ---------------------------------------------------------------------------
// embedding gather: x[row][0:768] = emb[ids[row]][0:768]
// ---------------------------------------------------------------------------
__global__ __launch_bounds__(192) void k_embed(const int* __restrict__ ids,
                                               const float* __restrict__ emb,
                                               float* __restrict__ x) {
  int row = blockIdx.x;
  int id = ids[row];
  const float4* src = (const float4*)(emb + (size_t)id * D_);
  float4* dst = (float4*)(x + (size_t)row * D_);
  dst[threadIdx.x] = src[threadIdx.x];
}

// ---------------------------------------------------------------------------
// generic fp32 GEMM: C[M,N] = A[M,K] @ W[N,K]^T + bias[N], act: 0 none 1 relu 2 sigmoid
// 128x128 tile, BK=16, 256 threads, 8x8 micro-tile.
// ---------------------------------------------------------------------------
#define GIDX(k, m) ((k)*144 + (m) + (((m) >> 5) << 2))

__global__ __launch_bounds__(256) void k_gemm(const float* __restrict__ A,
                                              const float* __restrict__ W,
                                              const float* __restrict__ bias,
                                              float* __restrict__ C,
                                              int M, int N, int K, int act) {
  __shared__ float As[2304];
  __shared__ float Bs[2304];
  int bm0 = blockIdx.y * 128, bn0 = blockIdx.x * 128;
  int tid = threadIdx.x;
  int tm = tid >> 4, tn = tid & 15;
  float acc[8][8];
#pragma unroll
  for (int i = 0; i < 8; ++i)
#pragma unroll
    for (int j = 0; j < 8; ++j) acc[i][j] = 0.f;

  for (int k0 = 0; k0 < K; k0 += 16) {
    __syncthreads();
#pragma unroll
    for (int j = 0; j < 2; ++j) {
      int f4 = tid + j * 256;          // 0..511
      int r = f4 >> 2;
      int kq = (f4 & 3) * 4;
      float4 va = *(const float4*)(A + (size_t)(bm0 + r) * K + k0 + kq);
      As[GIDX(kq + 0, r)] = va.x; As[GIDX(kq + 1, r)] = va.y;
      As[GIDX(kq + 2, r)] = va.z; As[GIDX(kq + 3, r)] = va.w;
      float4 vb = *(const float4*)(W + (size_t)(bn0 + r) * K + k0 + kq);
      Bs[GIDX(kq + 0, r)] = vb.x; Bs[GIDX(kq + 1, r)] = vb.y;
      Bs[GIDX(kq + 2, r)] = vb.z; Bs[GIDX(kq + 3, r)] = vb.w;
    }
    __syncthreads();
#pragma unroll
    for (int kk = 0; kk < 16; ++kk) {
      float a[8], b[8];
      *(float4*)&a[0] = *(const float4*)&As[GIDX(kk, tm * 8)];
      *(float4*)&a[4] = *(const float4*)&As[GIDX(kk, tm * 8 + 4)];
      *(float4*)&b[0] = *(const float4*)&Bs[GIDX(kk, tn * 8)];
      *(float4*)&b[4] = *(const float4*)&Bs[GIDX(kk, tn * 8 + 4)];
#pragma unroll
      for (int i = 0; i < 8; ++i)
#pragma unroll
        for (int j = 0; j < 8; ++j) acc[i][j] += a[i] * b[j];
    }
  }

  float bv[8];
#pragma unroll
  for (int j = 0; j < 8; ++j) bv[j] = bias[bn0 + tn * 8 + j];
#pragma unroll
  for (int i = 0; i < 8; ++i) {
    int row = bm0 + tm * 8 + i;
    float o[8];
#pragma unroll
    for (int j = 0; j < 8; ++j) {
      float v = acc[i][j] + bv[j];
      if (act == 1) v = fmaxf(v, 0.f);
      else if (act == 2) v = 1.f / (1.f + expf(-v));
      o[j] = v;
    }
    float* cp = C + (size_t)row * N + bn0 + tn * 8;
    *(float4*)cp = make_float4(o[0], o[1], o[2], o[3]);
    *(float4*)(cp + 4) = make_float4(o[4], o[5], o[6], o[7]);
  }
}

// ---------------------------------------------------------------------------
// highway combine (in place): x = t*hh + (1-t)*x
// ---------------------------------------------------------------------------
__global__ __launch_bounds__(256) void k_highway(float* __restrict__ x,
                                                 const float* __restrict__ hh,
                                                 const float* __restrict__ tt) {
  const int n4 = BS_ * D_ / 4;
  for (int i = blockIdx.x * 256 + threadIdx.x; i < n4; i += gridDim.x * 256) {
    float4 xv = ((const float4*)x)[i];
    float4 hv = ((const float4*)hh)[i];
    float4 tv = ((const float4*)tt)[i];
    xv.x = tv.x * hv.x + (1.f - tv.x) * xv.x;
    xv.y = tv.y * hv.y + (1.f - tv.y) * xv.y;
    xv.z = tv.z * hv.z + (1.f - tv.z) * xv.z;
    xv.w = tv.w * hv.w + (1.f - tv.w) * xv.w;
    ((float4*)x)[i] = xv;
  }
}

// ---------------------------------------------------------------------------
// multi-head attention. qkv: [4096][2304] (q|k|v). out: [4096][768].
// ---------------------------------------------------------------------------
__global__ __launch_bounds__(256) void k_attn(const float* __restrict__ qkv,
                                              float* __restrict__ out) {
  __shared__ float Qs[16 * 100];
  __shared__ float Ks[32 * 101];
  __shared__ float Ps[16 * 513];
  int bh = blockIdx.x;          // 0..63
  int b = bh >> 3, h = bh & 7;
  int q0 = blockIdx.y * 16;
  int tid = threadIdx.x;
  const float scale = 0.10206207261596577f;  // 1/sqrt(96)

  const float* qb = qkv + (size_t)(b * 512 + q0) * 2304 + h * 96;
  for (int i = tid; i < 16 * 96; i += 256) {
    int r = i / 96, c = i - r * 96;
    Qs[r * 100 + c] = qb[(size_t)r * 2304 + c];
  }
  int qi = tid >> 4, kseg = tid & 15;

  for (int kt = 0; kt < 16; ++kt) {
    __syncthreads();
    const float* kb = qkv + (size_t)(b * 512 + kt * 32) * 2304 + 768 + h * 96;
    for (int i = tid; i < 32 * 96; i += 256) {
      int r = i / 96, c = i - r * 96;
      Ks[r * 101 + c] = kb[(size_t)r * 2304 + c];
    }
    __syncthreads();
    int kj0 = kseg * 2;
    float s0 = 0.f, s1 = 0.f;
    const float* qrow = &Qs[qi * 100];
    const float* k0p = &Ks[kj0 * 101];
    const float* k1p = &Ks[(kj0 + 1) * 101];
#pragma unroll 8
    for (int d = 0; d < 96; ++d) {
      float qv = qrow[d];
      s0 += qv * k0p[d];
      s1 += qv * k1p[d];
    }
    Ps[qi * 513 + kt * 32 + kj0] = s0 * scale;
    Ps[qi * 513 + kt * 32 + kj0 + 1] = s1 * scale;
  }
  __syncthreads();

  {
    float m = -1e30f;
    for (int j = 0; j < 32; ++j) m = fmaxf(m, Ps[qi * 513 + kseg + j * 16]);
    m = fmaxf(m, __shfl_xor(m, 1)); m = fmaxf(m, __shfl_xor(m, 2));
    m = fmaxf(m, __shfl_xor(m, 4)); m = fmaxf(m, __shfl_xor(m, 8));
    float sum = 0.f;
    for (int j = 0; j < 32; ++j) {
      int idx = qi * 513 + kseg + j * 16;
      float e = expf(Ps[idx] - m);
      Ps[idx] = e;
      sum += e;
    }
    sum += __shfl_xor(sum, 1); sum += __shfl_xor(sum, 2);
    sum += __shfl_xor(sum, 4); sum += __shfl_xor(sum, 8);
    float inv = 1.f / sum;
    for (int j = 0; j < 32; ++j) Ps[qi * 513 + kseg + j * 16] *= inv;
  }

  float acc[6] = {0.f, 0.f, 0.f, 0.f, 0.f, 0.f};
  int d0 = kseg * 6;
  for (int kt = 0; kt < 16; ++kt) {
    __syncthreads();
    const float* vb = qkv + (size_t)(b * 512 + kt * 32) * 2304 + 1536 + h * 96;
    for (int i = tid; i < 32 * 96; i += 256) {
      int r = i / 96, c = i - r * 96;
      Ks[r * 101 + c] = vb[(size_t)r * 2304 + c];
    }
    __syncthreads();
#pragma unroll 4
    for (int kj = 0; kj < 32; ++kj) {
      float p = Ps[qi * 513 + kt * 32 + kj];
      const float* vrow = &Ks[kj * 101 + d0];
#pragma unroll
      for (int u = 0; u < 6; ++u) acc[u] += p * vrow[u];
    }
  }
  float* ob = out + (size_t)(b * 512 + q0 + qi) * 768 + h * 96 + d0;
#pragma unroll
  for (int u = 0; u < 6; ++u) ob[u] = acc[u];
}

// ---------------------------------------------------------------------------
// persistent BiLSTM recurrence, one layer (both dirs), 192 WGs x 256 threads.
// Whh slice (32 rows x 768) lives in LDS -> ~40 VGPR, no spill.
// thread = (rho = tid>>3 in 0..31, bb = tid&7). rho -> gate g=rho&3, u=rho>>2.
// Each thread computes one full 768-wide dot from LDS.
// Cross-XCD h exchange: sc1 (agent-scope) relaxed atomics, no L2 flushes.
// Barrier: per-WG flag array (monotonic), 96 parallel polls, no contention.
// ---------------------------------------------------------------------------
#define NWGD 96
__global__ __launch_bounds__(256) void k_lstm(const float* __restrict__ gates,
                                              const float* __restrict__ Whh,
                                              float* __restrict__ hbuf,
                                              float* __restrict__ hs,
                                              int* __restrict__ flags) {
  __shared__ float wlds[32 * 772];   // 96.5 KB, row stride 772 (=4 mod 32)
  __shared__ float hlds[8 * 772];    // 24.1 KB
  int tid = threadIdx.x;
  int wg = blockIdx.x;
  int dir = wg / NWGD;
  int grp = wg % NWGD;
  int rho = tid >> 3;                // 0..31
  int bb = tid & 7;                  // batch
  int g = rho & 3;
  int u = rho >> 2;                  // 0..7
  int hidden = grp * 8 + u;
  int wrow = g * 768 + hidden;

  // one-time: load this WG's 32 Whh rows into LDS (coalesced)
#pragma unroll
  for (int it = 0; it < 24; ++it) {
    int idx = it * 256 + tid;        // 0..6143 float4s
    int rL = idx / 192;              // 0..31
    int kq = idx - rL * 192;         // 0..191
    int gL = rL & 3, uL = rL >> 2;
    float4 v = *(const float4*)(Whh + ((size_t)dir * 3072 + gL * 768 + grp * 8 + uL) * 768 + kq * 4);
    *(float4*)&wlds[rL * 772 + kq * 4] = v;
  }

  float* hb = hbuf + (size_t)dir * 2 * 6144;   // [parity][bb][hidden]
  float cst = 0.f;
  const float* wp = &wlds[rho * 772];
  const float* hp = &hlds[bb * 772];
  __syncthreads();

  for (int step = 0; step < 512; ++step) {
    int t = dir ? (511 - step) : step;
    // issue gates value early (plain load, gates is immutable)
    float gqv = gates[((size_t)(bb * 512 + t)) * 6144 + dir * 3072 + wrow];

    // stage h(t) into LDS via device-coherent (sc1) loads (bypass stale L2)
#pragma unroll
    for (int i = 0; i < 6; ++i) {
      int idx = i * 256 + tid;       // 0..1535 float4s
      int b2 = idx / 192;
      int kq = idx - b2 * 192;
      const float* src = hb + (step & 1) * 6144 + b2 * 768 + kq * 4;
      float v0 = __hip_atomic_load(src + 0, __ATOMIC_RELAXED, __HIP_MEMORY_SCOPE_AGENT);
      float v1 = __hip_atomic_load(src + 1, __ATOMIC_RELAXED, __HIP_MEMORY_SCOPE_AGENT);
      float v2 = __hip_atomic_load(src + 2, __ATOMIC_RELAXED, __HIP_MEMORY_SCOPE_AGENT);
      float v3 = __hip_atomic_load(src + 3, __ATOMIC_RELAXED, __HIP_MEMORY_SCOPE_AGENT);
      *(float4*)&hlds[b2 * 772 + kq * 4] = make_float4(v0, v1, v2, v3);
    }
    __syncthreads();   // hlds ready

    // dot(w[rho], h[bb]) over 768, 8 independent accumulators
    float a0 = 0.f, a1 = 0.f, a2 = 0.f, a3 = 0.f, a4 = 0.f, a5 = 0.f, a6 = 0.f, a7 = 0.f;
#pragma unroll 4
    for (int k = 0; k < 768; k += 8) {
      float4 w0 = *(const float4*)(wp + k);
      float4 w1 = *(const float4*)(wp + k + 4);
      float4 h0 = *(const float4*)(hp + k);
      float4 h1 = *(const float4*)(hp + k + 4);
      a0 = fmaf(w0.x, h0.x, a0); a1 = fmaf(w0.y, h0.y, a1);
      a2 = fmaf(w0.z, h0.z, a2); a3 = fmaf(w0.w, h0.w, a3);
      a4 = fmaf(w1.x, h1.x, a4); a5 = fmaf(w1.y, h1.y, a5);
      a6 = fmaf(w1.z, h1.z, a6); a7 = fmaf(w1.w, h1.w, a7);
    }
    float gsum = ((a0 + a1) + (a2 + a3)) + ((a4 + a5) + (a6 + a7)) + gqv;

    // gather 4 gate values: lanes (u*4+g)*8+bb, g strided by 8 within wave
    float g1 = __shfl_down(gsum, 8);
    float g2 = __shfl_down(gsum, 16);
    float g3 = __shfl_down(gsum, 24);
    if ((rho & 3) == 0) {
      float i_ = 1.f / (1.f + expf(-gsum));
      float f_ = 1.f / (1.f + expf(-g1));
      float ci = tanhf(g2);
      float o_ = 1.f / (1.f + expf(-g3));
      cst = f_ * cst + i_ * ci;
      float hnew = o_ * tanhf(cst);
      // device-coherent store (reaches LLC; drained by next __syncthreads)
      __hip_atomic_store(hb + ((step + 1) & 1) * 6144 + bb * 768 + hidden, hnew,
                         __ATOMIC_RELAXED, __HIP_MEMORY_SCOPE_AGENT);
      hs[((size_t)(bb * 512 + t)) * 1536 + dir * 768 + hidden] = hnew;
    }

    // barrier: per-WG monotonic flag, contention-free
    __syncthreads();   // drains every wave's vmcnt (incl. sc1 h stores)
    if (tid == 0)
      __hip_atomic_store(&flags[wg * 32], step + 1, __ATOMIC_RELAXED, __HIP_MEMORY_SCOPE_AGENT);
    if (tid < NWGD) {
      const int* fp = &flags[(dir * NWGD + tid) * 32];
      while (__hip_atomic_load(fp, __ATOMIC_RELAXED, __HIP_MEMORY_SCOPE_AGENT) <= step)
        __builtin_amdgcn_s_sleep(2);
    }
    __syncthreads();   // all flags observed -> remote h stores are at LLC
  }
}

// ---------------------------------------------------------------------------
// fc: em[4096][9] = A[4096][1536] @ fcW[9][1536]^T + fcb. Wave per row.
// ---------------------------------------------------------------------------
__global__ __launch_bounds__(256) void k_fc(const float* __restrict__ A,
                                            const float* __restrict__ Wf,
                                            const float* __restrict__ bf,
                                            float* __restrict__ out) {
  __shared__ float Wl[9 * 1536];
  int tid = threadIdx.x;
  for (int i = tid; i < 9 * 1536; i += 256) Wl[i] = Wf[i];
  __syncthreads();
  int lane = tid & 63, wv = tid >> 6;
  int row = blockIdx.x * 4 + wv;
  const float* a = A + (size_t)row * 1536;
  float acc[9];
#pragma unroll
  for (int c = 0; c < 9; ++c) acc[c] = 0.f;
  for (int i = 0; i < 24; ++i) {
    float av = a[lane + i * 64];
#pragma unroll
    for (int c = 0; c < 9; ++c) acc[c] += av * Wl[c * 1536 + lane + i * 64];
  }
#pragma unroll
  for (int c = 0; c < 9; ++c) {
#pragma unroll
    for (int m = 1; m < 64; m <<= 1) acc[c] += __shfl_xor(acc[c], m);
  }
  if (lane == 0) {
#pragma unroll
    for (int c = 0; c < 9; ++c) out[(size_t)row * 9 + c] = acc[c] + bf[c];
  }
}

// ---------------------------------------------------------------------------
// CRF: forward logsumexp + numerator + Viterbi + backtrace. Single block.
// ---------------------------------------------------------------------------
__global__ __launch_bounds__(128) void k_crf(const float* __restrict__ em,
                                             const int* __restrict__ labels,
                                             const float* __restrict__ cs,
                                             const float* __restrict__ ce,
                                             const float* __restrict__ ct,
                                             float* __restrict__ out) {
  __shared__ float trans[9][12];
  __shared__ float ab[2][8][9];
  __shared__ float vb[2][8][9];
  __shared__ unsigned char bps[511][8][9];
  __shared__ float red[128];
  __shared__ float lz[8];
  int tid = threadIdx.x;
  if (tid < 81) trans[tid / 9][tid % 9] = ct[tid];
  if (tid < 72) {
    int b = tid / 9, c = tid % 9;
    float v = cs[c] + em[(b * 512) * 9 + c];
    ab[0][b][c] = v;
    vb[0][b][c] = v;
  }
  __syncthreads();
  for (int t = 1; t < 512; ++t) {
    int rp = (t - 1) & 1, wp = t & 1;
    if (tid < 72) {
      int b = tid / 9, cn = tid % 9;
      float e = em[(b * 512 + t) * 9 + cn];
      float m = -1e30f, vm = -1e30f;
      int bp = 0;
#pragma unroll
      for (int cp = 0; cp < 9; ++cp) {
        float x = ab[rp][b][cp] + trans[cp][cn];
        m = fmaxf(m, x);
        float y = vb[rp][b][cp] + trans[cp][cn];
        if (y > vm) { vm = y; bp = cp; }
      }
      float ssum = 0.f;
#pragma unroll
      for (int cp = 0; cp < 9; ++cp)
        ssum += expf(ab[rp][b][cp] + trans[cp][cn] - m);
      ab[wp][b][cn] = m + logf(ssum) + e;
      vb[wp][b][cn] = vm + e;
      bps[t - 1][b][cn] = (unsigned char)bp;
    }
    __syncthreads();
  }
  float part = 0.f;
  for (int idx = tid; idx < 4096; idx += 128) {
    int b = idx >> 9, t = idx & 511;
    int tg = labels[b * 512 + t];
    part += em[(b * 512 + t) * 9 + tg];
    if (t < 511) part += trans[tg][labels[b * 512 + t + 1]];
  }
  if (tid < 8) part += cs[labels[tid * 512]] + ce[labels[tid * 512 + 511]];
  red[tid] = part;
  __syncthreads();
  for (int s2 = 64; s2 > 0; s2 >>= 1) {
    if (tid < s2) red[tid] += red[tid + s2];
    __syncthreads();
  }
  if (tid < 8) {
    int b = tid;
    float m = -1e30f;
#pragma unroll
    for (int c = 0; c < 9; ++c) m = fmaxf(m, ab[1][b][c] + ce[c]);
    float ssum = 0.f;
#pragma unroll
    for (int c = 0; c < 9; ++c) ssum += expf(ab[1][b][c] + ce[c] - m);
    lz[b] = m + logf(ssum);
  }
  __syncthreads();
  if (tid == 0) {
    float z = 0.f;
#pragma unroll
    for (int b = 0; b < 8; ++b) z += lz[b];
    out[0] = -(red[0] - z);
  }
  if (tid < 8) {
    int b = tid;
    float bv2 = vb[1][b][0] + ce[0];
    int best = 0;
#pragma unroll
    for (int c = 1; c < 9; ++c) {
      float y = vb[1][b][c] + ce[c];
      if (y > bv2) { bv2 = y; best = c; }
    }
    out[1 + b * 512 + 511] = (float)best;
    int tg = best;
    for (int t = 510; t >= 0; --t) {
      tg = bps[t][b][tg];
      out[1 + b * 512 + t] = (float)tg;
    }
  }
}

// ---------------------------------------------------------------------------
extern "C" void kernel_launch(void* const* d_in, const int* in_sizes, int n_in,
                              void* d_out, int out_size, void* d_ws, size_t ws_size,
                              hipStream_t stream) {
  (void)in_sizes; (void)n_in; (void)out_size; (void)ws_size;
  const int*   ids    = (const int*)d_in[0];
  const int*   labels = (const int*)d_in[1];
  const float* emb    = (const float*)d_in[2];
  const float* hwWh   = (const float*)d_in[3];
  const float* hwbh   = (const float*)d_in[4];
  const float* hwWt   = (const float*)d_in[5];
  const float* hwbt   = (const float*)d_in[6];
  const float* ipw    = (const float*)d_in[7];
  const float* ipb    = (const float*)d_in[8];
  const float* opw    = (const float*)d_in[9];
  const float* opb    = (const float*)d_in[10];
  const float* l0Wih  = (const float*)d_in[11];
  const float* l0Whh  = (const float*)d_in[12];
  const float* l0b    = (const float*)d_in[13];
  const float* l1Wih  = (const float*)d_in[14];
  const float* l1Whh  = (const float*)d_in[15];
  const float* l1b    = (const float*)d_in[16];
  const float* fcW    = (const float*)d_in[17];
  const float* fcb    = (const float*)d_in[18];
  const float* cs     = (const float*)d_in[19];
  const float* ce     = (const float*)d_in[20];
  const float* ct     = (const float*)d_in[21];

  float* ws   = (float*)d_ws;
  float* x0   = ws;                 // 3,145,728
  float* gbuf = ws + 3145728;       // 25,165,824 (hh|tt, later qkv, later gates)
  float* hh   = gbuf;
  float* tt   = gbuf + 3145728;
  float* qkv  = gbuf + 6291456;
  float* x1   = ws + 28311552;      // 3,145,728
  float* hs0  = ws + 31457280;      // 6,291,456
  float* hs1  = ws + 37748736;      // 6,291,456
  float* em   = ws + 44040192;      // 36,864
  float* hbuf = ws + 44077056;      // 24,576
  int*   flags = (int*)(ws + 44101632);  // 192*32 ints

  dim3 g768(6, 32), g2304(18, 32), g6144(48, 32);

  k_embed<<<BS_, 192, 0, stream>>>(ids, emb, x0);
  k_gemm<<<g768, 256, 0, stream>>>(x0, hwWh, hwbh, hh, BS_, 768, 768, 1);
  k_gemm<<<g768, 256, 0, stream>>>(x0, hwWt, hwbt, tt, BS_, 768, 768, 2);
  k_highway<<<768, 256, 0, stream>>>(x0, hh, tt);
  k_gemm<<<g2304, 256, 0, stream>>>(x0, ipw, ipb, qkv, BS_, 2304, 768, 0);
  k_attn<<<dim3(64, 32), 256, 0, stream>>>(qkv, x0);
  k_gemm<<<g768, 256, 0, stream>>>(x0, opw, opb, x1, BS_, 768, 768, 0);

  k_gemm<<<g6144, 256, 0, stream>>>(x1, l0Wih, l0b, gbuf, BS_, 6144, 768, 0);
  hipMemsetAsync(hbuf, 0, (24576 + 192 * 32) * sizeof(float), stream);
  k_lstm<<<192, 256, 0, stream>>>(gbuf, l0Whh, hbuf, hs0, flags);

  k_gemm<<<g6144, 256, 0, stream>>>(hs0, l1Wih, l1b, gbuf, BS_, 6144, 1536, 0);
  hipMemsetAsync(hbuf, 0, (24576 + 192 * 32) * sizeof(float), stream);
  k_lstm<<<192, 256, 0, stream>>>(gbuf, l1Whh, hbuf, hs1, flags);

  k_fc<<<1024, 256, 0, stream>>>(hs1, fcW, fcb, em);
  k_crf<<<1, 128, 0, stream>>>(em, labels, cs, ce, ct, (float*)d_out);
}

// Round 3
// 8108.869 us; speedup vs baseline: 13.6029x; 1.2063x over previous
//
#include <hip/hip_runtime.h>
#include <cstdint>

#define B_   8
#define S_   512
#define D_   768
#define C_   9
#define BS_  4096   // B*S

typedef unsigned long long u64;

// ---------------------------------------------------------------------------
// embedding gather: x[row][0:768] = emb[ids[row]][0:768]
// ---------------------------------------------------------------------------
__global__ __launch_bounds__(192) void k_embed(const int* __restrict__ ids,
                                               const float* __restrict__ emb,
                                               float* __restrict__ x) {
  int row = blockIdx.x;
  int id = ids[row];
  const float4* src = (const float4*)(emb + (size_t)id * D_);
  float4* dst = (float4*)(x + (size_t)row * D_);
  dst[threadIdx.x] = src[threadIdx.x];
}

// ---------------------------------------------------------------------------
// generic fp32 GEMM: C[M,N] = A[M,K] @ W[N,K]^T + bias[N]
// act: 0 none 1 relu 2 sigmoid ; mode: 0 row-major C, 1 lstm-gates layout
// gates layout: C[((dir*512+t)*96+grp)*256 + u*32 + g*8 + bb]
//   where m=bb*512+t, n=dir*3072+g*768+grp*8+u
// ---------------------------------------------------------------------------
#define GIDX(k, m) ((k)*144 + (m) + (((m) >> 5) << 2))

__global__ __launch_bounds__(256) void k_gemm(const float* __restrict__ A,
                                              const float* __restrict__ W,
                                              const float* __restrict__ bias,
                                              float* __restrict__ C,
                                              int M, int N, int K, int act, int mode) {
  __shared__ float As[2304];
  __shared__ float Bs[2304];
  int bm0 = blockIdx.y * 128, bn0 = blockIdx.x * 128;
  int tid = threadIdx.x;
  int tm = tid >> 4, tn = tid & 15;
  float acc[8][8];
#pragma unroll
  for (int i = 0; i < 8; ++i)
#pragma unroll
    for (int j = 0; j < 8; ++j) acc[i][j] = 0.f;

  for (int k0 = 0; k0 < K; k0 += 16) {
    __syncthreads();
#pragma unroll
    for (int j = 0; j < 2; ++j) {
      int f4 = tid + j * 256;          // 0..511
      int r = f4 >> 2;
      int kq = (f4 & 3) * 4;
      float4 va = *(const float4*)(A + (size_t)(bm0 + r) * K + k0 + kq);
      As[GIDX(kq + 0, r)] = va.x; As[GIDX(kq + 1, r)] = va.y;
      As[GIDX(kq + 2, r)] = va.z; As[GIDX(kq + 3, r)] = va.w;
      float4 vb = *(const float4*)(W + (size_t)(bn0 + r) * K + k0 + kq);
      Bs[GIDX(kq + 0, r)] = vb.x; Bs[GIDX(kq + 1, r)] = vb.y;
      Bs[GIDX(kq + 2, r)] = vb.z; Bs[GIDX(kq + 3, r)] = vb.w;
    }
    __syncthreads();
#pragma unroll
    for (int kk = 0; kk < 16; ++kk) {
      float a[8], b[8];
      *(float4*)&a[0] = *(const float4*)&As[GIDX(kk, tm * 8)];
      *(float4*)&a[4] = *(const float4*)&As[GIDX(kk, tm * 8 + 4)];
      *(float4*)&b[0] = *(const float4*)&Bs[GIDX(kk, tn * 8)];
      *(float4*)&b[4] = *(const float4*)&Bs[GIDX(kk, tn * 8 + 4)];
#pragma unroll
      for (int i = 0; i < 8; ++i)
#pragma unroll
        for (int j = 0; j < 8; ++j) acc[i][j] += a[i] * b[j];
    }
  }

  float bv[8];
#pragma unroll
  for (int j = 0; j < 8; ++j) bv[j] = bias[bn0 + tn * 8 + j];
#pragma unroll
  for (int i = 0; i < 8; ++i) {
    int row = bm0 + tm * 8 + i;
    float o[8];
#pragma unroll
    for (int j = 0; j < 8; ++j) {
      float v = acc[i][j] + bv[j];
      if (act == 1) v = fmaxf(v, 0.f);
      else if (act == 2) v = 1.f / (1.f + expf(-v));
      o[j] = v;
    }
    if (mode == 0) {
      float* cp = C + (size_t)row * N + bn0 + tn * 8;
      *(float4*)cp = make_float4(o[0], o[1], o[2], o[3]);
      *(float4*)(cp + 4) = make_float4(o[4], o[5], o[6], o[7]);
    } else {
      int bb = row >> 9, t = row & 511;
#pragma unroll
      for (int j = 0; j < 8; ++j) {
        unsigned n = bn0 + tn * 8 + j;
        unsigned dir = n / 3072u;
        unsigned n2 = n - dir * 3072u;
        unsigned g = n2 / 768u;
        unsigned rem = n2 - g * 768u;
        unsigned grp = rem >> 3, u = rem & 7;
        C[(((size_t)(dir * 512 + t) * 96 + grp) << 8) + u * 32 + g * 8 + bb] = o[j];
      }
    }
  }
}

// ---------------------------------------------------------------------------
// highway combine (in place): x = t*hh + (1-t)*x
// ---------------------------------------------------------------------------
__global__ __launch_bounds__(256) void k_highway(float* __restrict__ x,
                                                 const float* __restrict__ hh,
                                                 const float* __restrict__ tt) {
  const int n4 = BS_ * D_ / 4;
  for (int i = blockIdx.x * 256 + threadIdx.x; i < n4; i += gridDim.x * 256) {
    float4 xv = ((const float4*)x)[i];
    float4 hv = ((const float4*)hh)[i];
    float4 tv = ((const float4*)tt)[i];
    xv.x = tv.x * hv.x + (1.f - tv.x) * xv.x;
    xv.y = tv.y * hv.y + (1.f - tv.y) * xv.y;
    xv.z = tv.z * hv.z + (1.f - tv.z) * xv.z;
    xv.w = tv.w * hv.w + (1.f - tv.w) * xv.w;
    ((float4*)x)[i] = xv;
  }
}

// ---------------------------------------------------------------------------
// multi-head attention. qkv: [4096][2304] (q|k|v). out: [4096][768].
// ---------------------------------------------------------------------------
__global__ __launch_bounds__(256) void k_attn(const float* __restrict__ qkv,
                                              float* __restrict__ out) {
  __shared__ float Qs[16 * 100];
  __shared__ float Ks[32 * 101];
  __shared__ float Ps[16 * 513];
  int bh = blockIdx.x;          // 0..63
  int b = bh >> 3, h = bh & 7;
  int q0 = blockIdx.y * 16;
  int tid = threadIdx.x;
  const float scale = 0.10206207261596577f;  // 1/sqrt(96)

  const float* qb = qkv + (size_t)(b * 512 + q0) * 2304 + h * 96;
  for (int i = tid; i < 16 * 96; i += 256) {
    int r = i / 96, c = i - r * 96;
    Qs[r * 100 + c] = qb[(size_t)r * 2304 + c];
  }
  int qi = tid >> 4, kseg = tid & 15;

  for (int kt = 0; kt < 16; ++kt) {
    __syncthreads();
    const float* kb = qkv + (size_t)(b * 512 + kt * 32) * 2304 + 768 + h * 96;
    for (int i = tid; i < 32 * 96; i += 256) {
      int r = i / 96, c = i - r * 96;
      Ks[r * 101 + c] = kb[(size_t)r * 2304 + c];
    }
    __syncthreads();
    int kj0 = kseg * 2;
    float s0 = 0.f, s1 = 0.f;
    const float* qrow = &Qs[qi * 100];
    const float* k0p = &Ks[kj0 * 101];
    const float* k1p = &Ks[(kj0 + 1) * 101];
#pragma unroll 8
    for (int d = 0; d < 96; ++d) {
      float qv = qrow[d];
      s0 += qv * k0p[d];
      s1 += qv * k1p[d];
    }
    Ps[qi * 513 + kt * 32 + kj0] = s0 * scale;
    Ps[qi * 513 + kt * 32 + kj0 + 1] = s1 * scale;
  }
  __syncthreads();

  {
    float m = -1e30f;
    for (int j = 0; j < 32; ++j) m = fmaxf(m, Ps[qi * 513 + kseg + j * 16]);
    m = fmaxf(m, __shfl_xor(m, 1)); m = fmaxf(m, __shfl_xor(m, 2));
    m = fmaxf(m, __shfl_xor(m, 4)); m = fmaxf(m, __shfl_xor(m, 8));
    float sum = 0.f;
    for (int j = 0; j < 32; ++j) {
      int idx = qi * 513 + kseg + j * 16;
      float e = expf(Ps[idx] - m);
      Ps[idx] = e;
      sum += e;
    }
    sum += __shfl_xor(sum, 1); sum += __shfl_xor(sum, 2);
    sum += __shfl_xor(sum, 4); sum += __shfl_xor(sum, 8);
    float inv = 1.f / sum;
    for (int j = 0; j < 32; ++j) Ps[qi * 513 + kseg + j * 16] *= inv;
  }

  float acc[6] = {0.f, 0.f, 0.f, 0.f, 0.f, 0.f};
  int d0 = kseg * 6;
  for (int kt = 0; kt < 16; ++kt) {
    __syncthreads();
    const float* vb = qkv + (size_t)(b * 512 + kt * 32) * 2304 + 1536 + h * 96;
    for (int i = tid; i < 32 * 96; i += 256) {
      int r = i / 96, c = i - r * 96;
      Ks[r * 101 + c] = vb[(size_t)r * 2304 + c];
    }
    __syncthreads();
#pragma unroll 4
    for (int kj = 0; kj < 32; ++kj) {
      float p = Ps[qi * 513 + kt * 32 + kj];
      const float* vrow = &Ks[kj * 101 + d0];
#pragma unroll
      for (int u = 0; u < 6; ++u) acc[u] += p * vrow[u];
    }
  }
  float* ob = out + (size_t)(b * 512 + q0 + qi) * 768 + h * 96 + d0;
#pragma unroll
  for (int u = 0; u < 6; ++u) ob[u] = acc[u];
}

// ---------------------------------------------------------------------------
// persistent BiLSTM recurrence, one layer (both dirs), 192 WGs x 256 threads.
// Whh lives in REGISTERS: thread (u=tid>>5, ks=tid&31) holds w4[4 gates][6 jj]
// for rows {g*768 + grp*8 + u} and interleaved k = 128*jj + ks*4 .. +3.
// Per step: h (8x768) staged to LDS; 48 b128 h-reads/thread; 768 FMA;
// 5-stage shuffle reduce-scatter lands gate (g=ks>>3, bb=ks&7) on lane ks.
// gates input layout: [(dir*512+t)][grp 96][tid 256] (coalesced 1 load/thread).
// ---------------------------------------------------------------------------
#define NWGD 96
__global__ __launch_bounds__(256, 1) void k_lstm(const float* __restrict__ gates,
                                                 const float* __restrict__ Whh,
                                                 float* __restrict__ hbuf,
                                                 float* __restrict__ hs,
                                                 int* __restrict__ flags) {
  __shared__ float hlds[8 * 772];    // 24.7 KB, per-bb stride 772 (=4 mod 32)
  int tid = threadIdx.x;
  int wg = blockIdx.x;
  int dir = wg / NWGD;
  int grp = wg % NWGD;
  int rg = tid >> 5;                 // unit u within group, 0..7
  int ks = tid & 31;                 // k-slice

  // load my weight tile into registers (96 VGPRs), coalesced along ks
  float4 w4[4][6];
#pragma unroll
  for (int j = 0; j < 4; ++j) {
    const float* wp = Whh + ((size_t)dir * 3072 + j * 768 + grp * 8 + rg) * 768 + ks * 4;
#pragma unroll
    for (int jj = 0; jj < 6; ++jj)
      w4[j][jj] = *(const float4*)(wp + jj * 128);
  }

  float* hb = hbuf + (size_t)dir * 2 * 6144;   // [parity][bb][768]
  const float* gbase = gates + (size_t)dir * 512 * 24576 + grp * 256 + tid;
  int* barp = flags;
  float cst = 0.f;
  const float* hp = hlds + ks * 4;

  for (int step = 0; step < 512; ++step) {
    int t = dir ? (511 - step) : step;
    float gqv = gbase[(size_t)t * 24576];

    // stage h(t) into LDS via agent-scope (sc1) 8B loads
#pragma unroll
    for (int i = 0; i < 3; ++i) {
      int idx = i * 256 + tid;            // 0..767 float8 chunks? -> 768*8B pairs
      int b2 = idx / 96;                  // 0..7
      int kq = (idx - b2 * 96) * 8;       // 0..760 step 8
      const u64* src = (const u64*)(hb + (step & 1) * 6144 + b2 * 768 + kq);
      u64 lo = __hip_atomic_load(src + 0, __ATOMIC_RELAXED, __HIP_MEMORY_SCOPE_AGENT);
      u64 hi = __hip_atomic_load(src + 1, __ATOMIC_RELAXED, __HIP_MEMORY_SCOPE_AGENT);
      u64 lo2 = __hip_atomic_load(src + 2, __ATOMIC_RELAXED, __HIP_MEMORY_SCOPE_AGENT);
      u64 hi2 = __hip_atomic_load(src + 3, __ATOMIC_RELAXED, __HIP_MEMORY_SCOPE_AGENT);
      float* dst = &hlds[b2 * 772 + kq];
      *(u64*)(dst + 0) = lo;
      *(u64*)(dst + 2) = hi;
      *(u64*)(dst + 4) = lo2;
      *(u64*)(dst + 6) = hi2;
    }
    __syncthreads();   // hlds ready

    // partials: v[g*8+bb] over my 24-wide interleaved k-slice
    float v[32];
#pragma unroll
    for (int i = 0; i < 32; ++i) v[i] = 0.f;
#pragma unroll
    for (int jj = 0; jj < 6; ++jj) {
#pragma unroll
      for (int b2 = 0; b2 < 8; ++b2) {
        float4 hv = *(const float4*)(hp + b2 * 772 + jj * 128);
#pragma unroll
        for (int j = 0; j < 4; ++j) {
          float4 w = w4[j][jj];
          v[j * 8 + b2] = fmaf(w.x, hv.x, v[j * 8 + b2]);
          v[j * 8 + b2] = fmaf(w.y, hv.y, v[j * 8 + b2]);
          v[j * 8 + b2] = fmaf(w.z, hv.z, v[j * 8 + b2]);
          v[j * 8 + b2] = fmaf(w.w, hv.w, v[j * 8 + b2]);
        }
      }
    }

    // reduce-scatter across 32 kslices: lane ks ends with sum for idx=ks
    {
      bool hi = (ks & 16) != 0;
#pragma unroll
      for (int i = 0; i < 16; ++i) {
        float keep = hi ? v[i + 16] : v[i];
        float send = hi ? v[i] : v[i + 16];
        v[i] = keep + __shfl_xor(send, 16);
      }
    }
    {
      bool hi = (ks & 8) != 0;
#pragma unroll
      for (int i = 0; i < 8; ++i) {
        float keep = hi ? v[i + 8] : v[i];
        float send = hi ? v[i] : v[i + 8];
        v[i] = keep + __shfl_xor(send, 8);
      }
    }
    {
      bool hi = (ks & 4) != 0;
#pragma unroll
      for (int i = 0; i < 4; ++i) {
        float keep = hi ? v[i + 4] : v[i];
        float send = hi ? v[i] : v[i + 4];
        v[i] = keep + __shfl_xor(send, 4);
      }
    }
    {
      bool hi = (ks & 2) != 0;
#pragma unroll
      for (int i = 0; i < 2; ++i) {
        float keep = hi ? v[i + 2] : v[i];
        float send = hi ? v[i] : v[i + 2];
        v[i] = keep + __shfl_xor(send, 2);
      }
    }
    {
      bool hi = (ks & 1) != 0;
      float keep = hi ? v[1] : v[0];
      float send = hi ? v[0] : v[1];
      v[0] = keep + __shfl_xor(send, 1);
    }

    float gv = v[0] + gqv;            // lane ks: gate g=ks>>3 for batch bb=ks&7
    float gf = __shfl_down(gv, 8);
    float gg = __shfl_down(gv, 16);
    float go = __shfl_down(gv, 24);
    if (ks < 8) {                     // owner of (unit=rg, bb=ks)
      float i_ = 1.f / (1.f + expf(-gv));
      float f_ = 1.f / (1.f + expf(-gf));
      float ci = tanhf(gg);
      float o_ = 1.f / (1.f + expf(-go));
      cst = f_ * cst + i_ * ci;
      float hnew = o_ * tanhf(cst);
      int hidden = grp * 8 + rg;
      __hip_atomic_store(hb + ((step + 1) & 1) * 6144 + ks * 768 + hidden, hnew,
                         __ATOMIC_RELAXED, __HIP_MEMORY_SCOPE_AGENT);
      hs[((size_t)(ks * 512 + t)) * 1536 + dir * 768 + hidden] = hnew;
    }

    // per-WG monotonic flag barrier (per direction)
    __syncthreads();   // drains every wave's outstanding stores
    if (tid == 0)
      __hip_atomic_store(&barp[wg * 32], step + 1, __ATOMIC_RELAXED, __HIP_MEMORY_SCOPE_AGENT);
    if (tid < NWGD) {
      const int* fp = &barp[(dir * NWGD + tid) * 32];
      while (__hip_atomic_load(fp, __ATOMIC_RELAXED, __HIP_MEMORY_SCOPE_AGENT) <= step)
        __builtin_amdgcn_s_sleep(2);
    }
    __syncthreads();   // all flags observed -> remote h stores visible
  }
}

// ---------------------------------------------------------------------------
// fc: em[4096][9] = A[4096][1536] @ fcW[9][1536]^T + fcb. Wave per row.
// ---------------------------------------------------------------------------
__global__ __launch_bounds__(256) void k_fc(const float* __restrict__ A,
                                            const float* __restrict__ Wf,
                                            const float* __restrict__ bf,
                                            float* __restrict__ out) {
  __shared__ float Wl[9 * 1536];
  int tid = threadIdx.x;
  for (int i = tid; i < 9 * 1536; i += 256) Wl[i] = Wf[i];
  __syncthreads();
  int lane = tid & 63, wv = tid >> 6;
  int row = blockIdx.x * 4 + wv;
  const float* a = A + (size_t)row * 1536;
  float acc[9];
#pragma unroll
  for (int c = 0; c < 9; ++c) acc[c] = 0.f;
  for (int i = 0; i < 24; ++i) {
    float av = a[lane + i * 64];
#pragma unroll
    for (int c = 0; c < 9; ++c) acc[c] += av * Wl[c * 1536 + lane + i * 64];
  }
#pragma unroll
  for (int c = 0; c < 9; ++c) {
#pragma unroll
    for (int m = 1; m < 64; m <<= 1) acc[c] += __shfl_xor(acc[c], m);
  }
  if (lane == 0) {
#pragma unroll
    for (int c = 0; c < 9; ++c) out[(size_t)row * 9 + c] = acc[c] + bf[c];
  }
}

// ---------------------------------------------------------------------------
// CRF: forward logsumexp + numerator + Viterbi + backtrace. Single block.
// ---------------------------------------------------------------------------
__global__ __launch_bounds__(128) void k_crf(const float* __restrict__ em,
                                             const int* __restrict__ labels,
                                             const float* __restrict__ cs,
                                             const float* __restrict__ ce,
                                             const float* __restrict__ ct,
                                             float* __restrict__ out) {
  __shared__ float trans[9][12];
  __shared__ float ab[2][8][9];
  __shared__ float vb[2][8][9];
  __shared__ unsigned char bps[511][8][9];
  __shared__ float red[128];
  __shared__ float lz[8];
  int tid = threadIdx.x;
  if (tid < 81) trans[tid / 9][tid % 9] = ct[tid];
  if (tid < 72) {
    int b = tid / 9, c = tid % 9;
    float v = cs[c] + em[(b * 512) * 9 + c];
    ab[0][b][c] = v;
    vb[0][b][c] = v;
  }
  __syncthreads();
  for (int t = 1; t < 512; ++t) {
    int rp = (t - 1) & 1, wp = t & 1;
    if (tid < 72) {
      int b = tid / 9, cn = tid % 9;
      float e = em[(b * 512 + t) * 9 + cn];
      float m = -1e30f, vm = -1e30f;
      int bp = 0;
#pragma unroll
      for (int cp = 0; cp < 9; ++cp) {
        float x = ab[rp][b][cp] + trans[cp][cn];
        m = fmaxf(m, x);
        float y = vb[rp][b][cp] + trans[cp][cn];
        if (y > vm) { vm = y; bp = cp; }
      }
      float ssum = 0.f;
#pragma unroll
      for (int cp = 0; cp < 9; ++cp)
        ssum += expf(ab[rp][b][cp] + trans[cp][cn] - m);
      ab[wp][b][cn] = m + logf(ssum) + e;
      vb[wp][b][cn] = vm + e;
      bps[t - 1][b][cn] = (unsigned char)bp;
    }
    __syncthreads();
  }
  float part = 0.f;
  for (int idx = tid; idx < 4096; idx += 128) {
    int b = idx >> 9, t = idx & 511;
    int tg = labels[b * 512 + t];
    part += em[(b * 512 + t) * 9 + tg];
    if (t < 511) part += trans[tg][labels[b * 512 + t + 1]];
  }
  if (tid < 8) part += cs[labels[tid * 512]] + ce[labels[tid * 512 + 511]];
  red[tid] = part;
  __syncthreads();
  for (int s2 = 64; s2 > 0; s2 >>= 1) {
    if (tid < s2) red[tid] += red[tid + s2];
    __syncthreads();
  }
  if (tid < 8) {
    int b = tid;
    float m = -1e30f;
#pragma unroll
    for (int c = 0; c < 9; ++c) m = fmaxf(m, ab[1][b][c] + ce[c]);
    float ssum = 0.f;
#pragma unroll
    for (int c = 0; c < 9; ++c) ssum += expf(ab[1][b][c] + ce[c] - m);
    lz[b] = m + logf(ssum);
  }
  __syncthreads();
  if (tid == 0) {
    float z = 0.f;
#pragma unroll
    for (int b = 0; b < 8; ++b) z += lz[b];
    out[0] = -(red[0] - z);
  }
  if (tid < 8) {
    int b = tid;
    float bv2 = vb[1][b][0] + ce[0];
    int best = 0;
#pragma unroll
    for (int c = 1; c < 9; ++c) {
      float y = vb[1][b][c] + ce[c];
      if (y > bv2) { bv2 = y; best = c; }
    }
    out[1 + b * 512 + 511] = (float)best;
    int tg = best;
    for (int t = 510; t >= 0; --t) {
      tg = bps[t][b][tg];
      out[1 + b * 512 + t] = (float)tg;
    }
  }
}

// ---------------------------------------------------------------------------
extern "C" void kernel_launch(void* const* d_in, const int* in_sizes, int n_in,
                              void* d_out, int out_size, void* d_ws, size_t ws_size,
                              hipStream_t stream) {
  (void)in_sizes; (void)n_in; (void)out_size; (void)ws_size;
  const int*   ids    = (const int*)d_in[0];
  const int*   labels = (const int*)d_in[1];
  const float* emb    = (const float*)d_in[2];
  const float* hwWh   = (const float*)d_in[3];
  const float* hwbh   = (const float*)d_in[4];
  const float* hwWt   = (const float*)d_in[5];
  const float* hwbt   = (const float*)d_in[6];
  const float* ipw    = (const float*)d_in[7];
  const float* ipb    = (const float*)d_in[8];
  const float* opw    = (const float*)d_in[9];
  const float* opb    = (const float*)d_in[10];
  const float* l0Wih  = (const float*)d_in[11];
  const float* l0Whh  = (const float*)d_in[12];
  const float* l0b    = (const float*)d_in[13];
  const float* l1Wih  = (const float*)d_in[14];
  const float* l1Whh  = (const float*)d_in[15];
  const float* l1b    = (const float*)d_in[16];
  const float* fcW    = (const float*)d_in[17];
  const float* fcb    = (const float*)d_in[18];
  const float* cs     = (const float*)d_in[19];
  const float* ce     = (const float*)d_in[20];
  const float* ct     = (const float*)d_in[21];

  float* ws   = (float*)d_ws;
  float* x0   = ws;                 // 3,145,728
  float* gbuf = ws + 3145728;       // 25,165,824 (hh|tt, later qkv, later gates)
  float* hh   = gbuf;
  float* tt   = gbuf + 3145728;
  float* qkv  = gbuf + 6291456;
  float* x1   = ws + 28311552;      // 3,145,728
  float* hs0  = ws + 31457280;      // 6,291,456
  float* hs1  = ws + 37748736;      // 6,291,456
  float* em   = ws + 44040192;      // 36,864
  float* hbuf = ws + 44077056;      // 24,576
  int*   flags = (int*)(ws + 44101632);  // 192*32 ints

  dim3 g768(6, 32), g2304(18, 32), g6144(48, 32);

  k_embed<<<BS_, 192, 0, stream>>>(ids, emb, x0);
  k_gemm<<<g768, 256, 0, stream>>>(x0, hwWh, hwbh, hh, BS_, 768, 768, 1, 0);
  k_gemm<<<g768, 256, 0, stream>>>(x0, hwWt, hwbt, tt, BS_, 768, 768, 2, 0);
  k_highway<<<768, 256, 0, stream>>>(x0, hh, tt);
  k_gemm<<<g2304, 256, 0, stream>>>(x0, ipw, ipb, qkv, BS_, 2304, 768, 0, 0);
  k_attn<<<dim3(64, 32), 256, 0, stream>>>(qkv, x0);
  k_gemm<<<g768, 256, 0, stream>>>(x0, opw, opb, x1, BS_, 768, 768, 0, 0);

  k_gemm<<<g6144, 256, 0, stream>>>(x1, l0Wih, l0b, gbuf, BS_, 6144, 768, 0, 1);
  hipMemsetAsync(hbuf, 0, (24576 + 192 * 32) * sizeof(float), stream);
  k_lstm<<<192, 256, 0, stream>>>(gbuf, l0Whh, hbuf, hs0, flags);

  k_gemm<<<g6144, 256, 0, stream>>>(hs0, l1Wih, l1b, gbuf, BS_, 6144, 1536, 0, 1);
  hipMemsetAsync(hbuf, 0, (24576 + 192 * 32) * sizeof(float), stream);
  k_lstm<<<192, 256, 0, stream>>>(gbuf, l1Whh, hbuf, hs1, flags);

  k_fc<<<1024, 256, 0, stream>>>(hs1, fcW, fcb, em);
  k_crf<<<1, 128, 0, stream>>>(em, labels, cs, ce, ct, (float*)d_out);
}